// Round 7
// baseline (534.609 us; speedup 1.0000x reference)
//
#include <hip/hip_runtime.h>
#include <hip/hip_cooperative_groups.h>
#include <cstddef>

namespace cg = cooperative_groups;

#define CC 128  // channels

// ===========================================================================
// Cooperative fused CSR build: zero -> hist -> scan -> fill, one dispatch.
// Grid MUST be 256 blocks x 256 threads (block b owns counts[b*256..+255]).
// Requires N <= 65536. counts is zeroed in-kernel and reused as fill cursor.
// ===========================================================================
__global__ __launch_bounds__(256) void build_csr_coop(
    const int* __restrict__ row, const int* __restrict__ col,
    const float* __restrict__ Lr, const float* __restrict__ Li,
    int* __restrict__ counts, int* __restrict__ offsets,
    int4* __restrict__ meta, int* __restrict__ bsum, int N, int E)
{
    cg::grid_group grid = cg::this_grid();
    __shared__ int s[256];
    const int t = threadIdx.x;
    const int b = blockIdx.x;
    const int gt = b * 256 + t;
    const int GT = 256 * 256;

    // phase 0: zero counts
    for (int i = gt; i < N; i += GT) counts[i] = 0;
    __threadfence();
    grid.sync();

    // phase 1: histogram
    for (int e = gt; e < E; e += GT) atomicAdd(counts + row[e], 1);
    __threadfence();
    grid.sync();

    // phase 2a: block-local inclusive scan of this block's 256 counts;
    // zero counts after reading (reuse as cursor); publish block sum.
    const int idx = gt;
    const int v = (idx < N) ? counts[idx] : 0;
    s[t] = v;
    __syncthreads();
    #pragma unroll
    for (int off = 1; off < 256; off <<= 1) {
        const int u = (t >= off) ? s[t - off] : 0;
        __syncthreads();
        s[t] += u;
        __syncthreads();
    }
    const int local_excl = s[t] - v;
    if (t == 255) bsum[b] = s[255];
    if (idx < N) counts[idx] = 0;
    __threadfence();
    grid.sync();

    // phase 2b: every block redundantly scans the 256 block sums,
    // adds its prefix, writes exclusive offsets.
    const int bs = bsum[t];
    s[t] = bs;
    __syncthreads();
    #pragma unroll
    for (int off = 1; off < 256; off <<= 1) {
        const int u = (t >= off) ? s[t - off] : 0;
        __syncthreads();
        s[t] += u;
        __syncthreads();
    }
    const int bpre = (b == 0) ? 0 : s[b - 1];
    if (idx < N) offsets[idx] = bpre + local_excl;
    __threadfence();
    grid.sync();

    // phase 3: fill CSR records {col, lr, li, pad}
    for (int e = gt; e < E; e += GT) {
        const int r = row[e];
        const int pos = offsets[r] + atomicAdd(counts + r, 1);
        meta[pos] = make_int4(col[e], __float_as_int(Lr[e]),
                              __float_as_int(Li[e]), 0);
    }
}

// ===========================================================================
// Y = [Xr;Xi] @ W, 8x8 register tile. 128-row x 128-col block tile,
// K staged in 32-chunks: AsT[32][132] (transposed, 16B-aligned, <=4-way
// store conflict) + Ws[32][128]. 256 threads = 16 row-groups x 16 col-groups.
// ===========================================================================
__global__ __launch_bounds__(256) void gemm_xw8(
    const float* __restrict__ Xr, const float* __restrict__ Xi,
    const float* __restrict__ W, float* __restrict__ Y, int N)
{
    __shared__ float AsT[32][132];   // [k][r], 16.9 KB
    __shared__ float Ws[32][128];    // 16 KB
    const int t = threadIdx.x;
    const int m0 = blockIdx.x * 128;
    const int M = 2 * N;
    const int tr = t >> 4;           // row group: rows tr*8..+7
    const int tc = t & 15;           // col group: cols tc*8..+7

    float acc[8][8];
    #pragma unroll
    for (int a = 0; a < 8; ++a)
        #pragma unroll
        for (int c = 0; c < 8; ++c) acc[a][c] = 0.f;

    for (int kc = 0; kc < 4; ++kc) {
        const int k0c = kc * 32;
        __syncthreads();   // previous chunk fully consumed
        // stage X chunk (128 rows x 32 k), transposed: 1024 float4, 4/thread
        #pragma unroll
        for (int q = 0; q < 4; ++q) {
            const int l = t + 256 * q;
            const int r = l >> 3;            // 0..127
            const int kg = (l & 7) * 4;      // 0..28
            const int m = m0 + r;
            float4 x = make_float4(0.f, 0.f, 0.f, 0.f);
            if (m < M) {
                const float* src = (m < N) ? (Xr + (size_t)m * CC)
                                           : (Xi + (size_t)(m - N) * CC);
                x = *(const float4*)(src + k0c + kg);
            }
            AsT[kg + 0][r] = x.x;
            AsT[kg + 1][r] = x.y;
            AsT[kg + 2][r] = x.z;
            AsT[kg + 3][r] = x.w;
        }
        // stage W chunk (rows k0c..+31, all 128 cols): 1024 float4, 4/thread
        #pragma unroll
        for (int q = 0; q < 4; ++q) {
            const int l = t + 256 * q;
            const int kk = l >> 5;           // 0..31
            const int c4 = (l & 31) * 4;     // 0..124
            *(float4*)&Ws[kk][c4] = *(const float4*)(W + (size_t)(k0c + kk) * CC + c4);
        }
        __syncthreads();

        #pragma unroll 2
        for (int kk = 0; kk < 32; ++kk) {
            const float4 a0 = *(const float4*)&AsT[kk][tr * 8];
            const float4 a1 = *(const float4*)&AsT[kk][tr * 8 + 4];
            const float4 w0 = *(const float4*)&Ws[kk][tc * 8];
            const float4 w1 = *(const float4*)&Ws[kk][tc * 8 + 4];
            const float ar[8] = {a0.x, a0.y, a0.z, a0.w, a1.x, a1.y, a1.z, a1.w};
            const float wc[8] = {w0.x, w0.y, w0.z, w0.w, w1.x, w1.y, w1.z, w1.w};
            #pragma unroll
            for (int a = 0; a < 8; ++a)
                #pragma unroll
                for (int c = 0; c < 8; ++c) acc[a][c] += ar[a] * wc[c];
        }
    }

    #pragma unroll
    for (int a = 0; a < 8; ++a) {
        const int m = m0 + tr * 8 + a;
        if (m >= M) continue;
        float4 o0 = {acc[a][0], acc[a][1], acc[a][2], acc[a][3]};
        float4 o1 = {acc[a][4], acc[a][5], acc[a][6], acc[a][7]};
        *(float4*)(Y + (size_t)m * CC + tc * 8)     = o0;
        *(float4*)(Y + (size_t)m * CC + tc * 8 + 4) = o1;
    }
}

// ===========================================================================
// Fused gather (UNCHANGED from round 6 — proven): out[n] = sum L_e*Y[col] + X[n]
// ===========================================================================
__device__ __forceinline__ void edge_acc(
    const int4 m, const float* __restrict__ Yr, const float* __restrict__ Yi,
    int lane, float2& aR, float2& aI)
{
    const float2 yr = *(const float2*)(Yr + (size_t)m.x * CC + 2 * lane);
    const float2 yi = *(const float2*)(Yi + (size_t)m.x * CC + 2 * lane);
    const float lr = __int_as_float(m.y);
    const float li = __int_as_float(m.z);
    aR.x += lr * yr.x - li * yi.x;
    aR.y += lr * yr.y - li * yi.y;
    aI.x += li * yr.x + lr * yi.x;
    aI.y += li * yr.y + lr * yi.y;
}

__global__ __launch_bounds__(256) void gather_fused(
    const float* __restrict__ Y,
    const float* __restrict__ Xr, const float* __restrict__ Xi,
    const int* __restrict__ offsets, const int4* __restrict__ meta,
    float* __restrict__ out, int N, int E)
{
    const int n = blockIdx.x * 4 + (threadIdx.x >> 6);
    if (n >= N) return;
    const int lane = threadIdx.x & 63;
    const float* Yr = Y;
    const float* Yi = Y + (size_t)N * CC;
    const int start = offsets[n];
    const int end   = (n + 1 < N) ? offsets[n + 1] : E;
    const int Em1 = E - 1;

    float2 aR = *(const float2*)(Xr + (size_t)n * CC + 2 * lane);
    float2 aI = *(const float2*)(Xi + (size_t)n * CC + 2 * lane);

    int4 m0 = meta[min(start + 0, Em1)];
    int4 m1 = meta[min(start + 1, Em1)];
    int4 m2 = meta[min(start + 2, Em1)];
    int4 m3 = meta[min(start + 3, Em1)];

    int j = start;
    for (; j + 4 <= end; j += 4) {
        const int4 n0 = meta[min(j + 4, Em1)];
        const int4 n1 = meta[min(j + 5, Em1)];
        const int4 n2 = meta[min(j + 6, Em1)];
        const int4 n3 = meta[min(j + 7, Em1)];
        const float2 yr0 = *(const float2*)(Yr + (size_t)m0.x * CC + 2 * lane);
        const float2 yi0 = *(const float2*)(Yi + (size_t)m0.x * CC + 2 * lane);
        const float2 yr1 = *(const float2*)(Yr + (size_t)m1.x * CC + 2 * lane);
        const float2 yi1 = *(const float2*)(Yi + (size_t)m1.x * CC + 2 * lane);
        const float2 yr2 = *(const float2*)(Yr + (size_t)m2.x * CC + 2 * lane);
        const float2 yi2 = *(const float2*)(Yi + (size_t)m2.x * CC + 2 * lane);
        const float2 yr3 = *(const float2*)(Yr + (size_t)m3.x * CC + 2 * lane);
        const float2 yi3 = *(const float2*)(Yi + (size_t)m3.x * CC + 2 * lane);
        {
            const float lr = __int_as_float(m0.y), li = __int_as_float(m0.z);
            aR.x += lr * yr0.x - li * yi0.x; aR.y += lr * yr0.y - li * yi0.y;
            aI.x += li * yr0.x + lr * yi0.x; aI.y += li * yr0.y + lr * yi0.y;
        }
        {
            const float lr = __int_as_float(m1.y), li = __int_as_float(m1.z);
            aR.x += lr * yr1.x - li * yi1.x; aR.y += lr * yr1.y - li * yi1.y;
            aI.x += li * yr1.x + lr * yi1.x; aI.y += li * yr1.y + lr * yi1.y;
        }
        {
            const float lr = __int_as_float(m2.y), li = __int_as_float(m2.z);
            aR.x += lr * yr2.x - li * yi2.x; aR.y += lr * yr2.y - li * yi2.y;
            aI.x += li * yr2.x + lr * yi2.x; aI.y += li * yr2.y + lr * yi2.y;
        }
        {
            const float lr = __int_as_float(m3.y), li = __int_as_float(m3.z);
            aR.x += lr * yr3.x - li * yi3.x; aR.y += lr * yr3.y - li * yi3.y;
            aI.x += li * yr3.x + lr * yi3.x; aI.y += li * yr3.y + lr * yi3.y;
        }
        m0 = n0; m1 = n1; m2 = n2; m3 = n3;
    }
    const int r = end - j;
    if (r > 0) edge_acc(m0, Yr, Yi, lane, aR, aI);
    if (r > 1) edge_acc(m1, Yr, Yi, lane, aR, aI);
    if (r > 2) edge_acc(m2, Yr, Yi, lane, aR, aI);

    *(float2*)(out + (size_t)n * CC + 2 * lane) = aR;
    *(float2*)(out + ((size_t)n + N) * CC + 2 * lane) = aI;
}

// ===========================================================================
// Non-cooperative fallback CSR build (round-6 proven)
// ===========================================================================
__global__ __launch_bounds__(256) void hist_rows(
    const int* __restrict__ row, int* __restrict__ counts, int E)
{
    const int e = blockIdx.x * 256 + threadIdx.x;
    if (e < E) atomicAdd(counts + row[e], 1);
}

__global__ __launch_bounds__(256) void scan_block_reduce(
    const int* __restrict__ counts, int* __restrict__ bsum, int N)
{
    __shared__ int s[256];
    const int t = threadIdx.x;
    const int idx = blockIdx.x * 256 + t;
    s[t] = (idx < N) ? counts[idx] : 0;
    __syncthreads();
    #pragma unroll
    for (int off = 128; off > 0; off >>= 1) {
        if (t < off) s[t] += s[t + off];
        __syncthreads();
    }
    if (t == 0) bsum[blockIdx.x] = s[0];
}

__global__ __launch_bounds__(256) void scan_bsum(
    const int* __restrict__ bsum, int* __restrict__ bpre, int NB)
{
    __shared__ int s[256];
    const int t = threadIdx.x;
    s[t] = (t < NB) ? bsum[t] : 0;
    __syncthreads();
    #pragma unroll
    for (int off = 1; off < 256; off <<= 1) {
        const int v = s[t];
        const int u = (t >= off) ? s[t - off] : 0;
        __syncthreads();
        s[t] = v + u;
        __syncthreads();
    }
    if (t < NB) bpre[t] = t ? s[t - 1] : 0;
}

__global__ __launch_bounds__(256) void scan_final(
    const int* __restrict__ counts, const int* __restrict__ bpre,
    int* __restrict__ offsets, int N)
{
    __shared__ int s[256];
    const int t = threadIdx.x;
    const int idx = blockIdx.x * 256 + t;
    const int v = (idx < N) ? counts[idx] : 0;
    s[t] = v;
    __syncthreads();
    #pragma unroll
    for (int off = 1; off < 256; off <<= 1) {
        const int a = s[t];
        const int u = (t >= off) ? s[t - off] : 0;
        __syncthreads();
        s[t] = a + u;
        __syncthreads();
    }
    if (idx < N) offsets[idx] = bpre[blockIdx.x] + s[t] - v;
}

__global__ __launch_bounds__(256) void fill_csr(
    const int* __restrict__ row, const int* __restrict__ col,
    const float* __restrict__ Lr, const float* __restrict__ Li,
    const int* __restrict__ offsets, int* __restrict__ cursor,
    int4* __restrict__ meta, int E)
{
    const int e = blockIdx.x * 256 + threadIdx.x;
    if (e >= E) return;
    const int r = row[e];
    const int pos = offsets[r] + atomicAdd(cursor + r, 1);
    meta[pos] = make_int4(col[e], __float_as_int(Lr[e]), __float_as_int(Li[e]), 0);
}

// Last-resort fallback: atomic scatter + in-place gemm (round-3 proven)
__global__ __launch_bounds__(256) void scatter_edges(
    const float* __restrict__ Xr, const float* __restrict__ Xi,
    const float* __restrict__ Lr, const float* __restrict__ Li,
    const int* __restrict__ row, const int* __restrict__ col,
    float* __restrict__ out, int N, int E)
{
    const int e = blockIdx.x * 4 + (threadIdx.x >> 6);
    if (e >= E) return;
    const int lane = threadIdx.x & 63;
    const int r = row[e], c = col[e];
    const float lr = Lr[e];
    const float li = Li[e];
    const float2 xr = *(const float2*)(Xr + (size_t)c * CC + 2 * lane);
    const float2 xi = *(const float2*)(Xi + (size_t)c * CC + 2 * lane);
    float* pr = out + (size_t)r * CC + 2 * lane;
    float* pi = out + ((size_t)r + N) * CC + 2 * lane;
    unsafeAtomicAdd(pr,     lr * xr.x - li * xi.x);
    unsafeAtomicAdd(pr + 1, lr * xr.y - li * xi.y);
    unsafeAtomicAdd(pi,     li * xr.x + lr * xi.x);
    unsafeAtomicAdd(pi + 1, li * xr.y + lr * xi.y);
}

__global__ __launch_bounds__(256) void gemm_inplace(
    float* __restrict__ io, const float* __restrict__ W,
    const float* __restrict__ Xp, int N)
{
    __shared__ float Ws[64 * CC];
    __shared__ float AsT[CC][36];
    const int t = threadIdx.x;
    const int m0 = blockIdx.x * 32;

    for (int ch = t; ch < 1024; ch += 256) {
        const int r  = ch >> 5;
        const int k0 = (ch & 31) * 4;
        const int m  = m0 + r;
        float4 q = make_float4(0.f, 0.f, 0.f, 0.f);
        if (m < N) q = *(const float4*)(io + (size_t)m * CC + k0);
        AsT[k0 + 0][r] = q.x;
        AsT[k0 + 1][r] = q.y;
        AsT[k0 + 2][r] = q.z;
        AsT[k0 + 3][r] = q.w;
    }

    const int cg = t & 31;
    const int rs = t >> 5;
    float s[4][4];
    #pragma unroll
    for (int a = 0; a < 4; ++a)
        #pragma unroll
        for (int b = 0; b < 4; ++b) s[a][b] = 0.f;

    for (int kc = 0; kc < 2; ++kc) {
        __syncthreads();
        {
            const float4* src = (const float4*)(W + (size_t)kc * 64 * CC);
            float4* dst = (float4*)Ws;
            #pragma unroll
            for (int i = 0; i < 8; ++i) dst[t + 256 * i] = src[t + 256 * i];
        }
        __syncthreads();
        #pragma unroll 4
        for (int kk = 0; kk < 64; ++kk) {
            const int k = kc * 64 + kk;
            const float4 av = *(const float4*)&AsT[k][rs * 4];
            const float4 wv = *(const float4*)&Ws[kk * CC + cg * 4];
            const float ar[4] = {av.x, av.y, av.z, av.w};
            const float wc[4] = {wv.x, wv.y, wv.z, wv.w};
            #pragma unroll
            for (int a = 0; a < 4; ++a)
                #pragma unroll
                for (int b = 0; b < 4; ++b) s[a][b] += ar[a] * wc[b];
        }
    }

    #pragma unroll
    for (int a = 0; a < 4; ++a) {
        const int m = m0 + rs * 4 + a;
        if (m >= N) continue;
        const float4 xv = *(const float4*)(Xp + (size_t)m * CC + cg * 4);
        float4 o;
        o.x = s[a][0] + xv.x;
        o.y = s[a][1] + xv.y;
        o.z = s[a][2] + xv.z;
        o.w = s[a][3] + xv.w;
        *(float4*)(io + (size_t)m * CC + cg * 4) = o;
    }
}

// ===========================================================================
extern "C" void kernel_launch(void* const* d_in, const int* in_sizes, int n_in,
                              void* d_out, int out_size, void* d_ws, size_t ws_size,
                              hipStream_t stream)
{
    const float* Xr = (const float*)d_in[0];
    const float* Xi = (const float*)d_in[1];
    const float* Lr = (const float*)d_in[2];
    const float* Li = (const float*)d_in[3];
    const float* W  = (const float*)d_in[4];
    const int* row = (const int*)d_in[5];
    const int* col = (const int*)d_in[6];
    float* out = (float*)d_out;

    int N = in_sizes[0] / CC;     // 50000
    int E = in_sizes[2];          // 800000

    const size_t y_bytes    = (size_t)2 * N * CC * sizeof(float);
    const size_t meta_bytes = (size_t)E * 16;
    const size_t int_bytes  = ((size_t)3 * N + 512) * sizeof(int);
    const size_t need_fused = y_bytes + meta_bytes + int_bytes;

    if (ws_size >= need_fused && N <= 65536) {
        float* Y       = (float*)d_ws;
        int4*  meta    = (int4*)((char*)d_ws + y_bytes);
        int*   counts  = (int*)((char*)d_ws + y_bytes + meta_bytes);
        int*   cursor  = counts + N;       // fallback-path cursor
        int*   offsets = cursor + N;
        int*   bsum    = offsets + N;
        int*   bpre    = bsum + 256;

        // --- fused CSR build (1 cooperative dispatch) ---
        const int* row_ = row; const int* col_ = col;
        const float* Lr_ = Lr; const float* Li_ = Li;
        int* counts_ = counts; int* offsets_ = offsets;
        int4* meta_ = meta; int* bsum_ = bsum;
        int N_ = N, E_ = E;
        void* args[] = {&row_, &col_, &Lr_, &Li_, &counts_, &offsets_,
                        &meta_, &bsum_, &N_, &E_};
        hipError_t cerr = hipLaunchCooperativeKernel(
            (const void*)build_csr_coop, dim3(256), dim3(256), args, 0, stream);
        if (cerr != hipSuccess) {
            // fallback: multi-kernel CSR build (proven round-6 path)
            const int NB = (N + 255) / 256;
            hipMemsetAsync(counts, 0, (size_t)2 * N * sizeof(int), stream);
            hist_rows<<<dim3((E + 255) / 256), dim3(256), 0, stream>>>(row, counts, E);
            scan_block_reduce<<<dim3(NB), dim3(256), 0, stream>>>(counts, bsum, N);
            scan_bsum<<<dim3(1), dim3(256), 0, stream>>>(bsum, bpre, NB);
            scan_final<<<dim3(NB), dim3(256), 0, stream>>>(counts, bpre, offsets, N);
            fill_csr<<<dim3((E + 255) / 256), dim3(256), 0, stream>>>(
                row, col, Lr, Li, offsets, cursor, meta, E);
        }
        gemm_xw8<<<dim3((2 * N + 127) / 128), dim3(256), 0, stream>>>(Xr, Xi, W, Y, N);
        gather_fused<<<dim3((N + 3) / 4), dim3(256), 0, stream>>>(
            Y, Xr, Xi, offsets, meta, out, N, E);
    } else {
        // minimal-footprint fallback: atomic scatter into zeroed out
        hipMemsetAsync(out, 0, (size_t)2 * N * CC * sizeof(float), stream);
        scatter_edges<<<dim3((E + 3) / 4), dim3(256), 0, stream>>>(
            Xr, Xi, Lr, Li, row, col, out, N, E);
        gemm_inplace<<<dim3((N + 31) / 32), dim3(256), 0, stream>>>(out, W, Xr, N);
        gemm_inplace<<<dim3((N + 31) / 32), dim3(256), 0, stream>>>(
            out + (size_t)N * CC, W, Xi, N);
    }
}